// Round 15
// baseline (209.046 us; speedup 1.0000x reference)
//
#include <hip/hip_runtime.h>

// GraphSAGE forward: bf16-plane storage, uint16 CSR col, rank-based atomic-free fill,
// packed (v_pk_add_f32) gather accumulation, single-kernel scan, atomic-free pooling,
// bf16x3-split MFMA matmuls.
#define N_NODES 50000
#define N_EDGES 800000
#define D 64
#define N_GRAPHS 512
#define D_TARGET 10
#define NB_SCAN ((N_NODES + 255) / 256)   // 196
#define TPAD 72                            // LDS tile row stride in bf16
#define EDGE_BLOCKS (N_EDGES / 256)        // 3125 (exact)
#define XSPLIT_BLOCKS EDGE_BLOCKS          // 3125
#define WPREP_BLOCKS 112                   // 7*4096/256

typedef __attribute__((ext_vector_type(8))) short short8;
typedef __attribute__((ext_vector_type(4))) float f32x4;
typedef __attribute__((ext_vector_type(2))) float f32x2;
typedef unsigned short ushort_t;
#define MFMA16(a, b, c) __builtin_amdgcn_mfma_f32_16x16x32_bf16(a, b, c, 0, 0, 0)

__device__ inline unsigned short bf16rne(float f) {
    unsigned u = __builtin_bit_cast(unsigned, f);
    u += 0x7FFFu + ((u >> 16) & 1u);
    return (unsigned short)(u >> 16);
}
__device__ inline float bf2f(unsigned short h) {
    unsigned u = ((unsigned)h) << 16;
    return __builtin_bit_cast(float, u);
}
// accumulate 8 bf16 (uint4) into 4 f32x2 accumulators (pairs -> v_pk_add_f32)
__device__ inline void acc8p(f32x2* a, uint4 v) {
    f32x2 t;
    t[0] = __builtin_bit_cast(float, v.x << 16);
    t[1] = __builtin_bit_cast(float, v.x & 0xFFFF0000u);
    a[0] += t;
    t[0] = __builtin_bit_cast(float, v.y << 16);
    t[1] = __builtin_bit_cast(float, v.y & 0xFFFF0000u);
    a[1] += t;
    t[0] = __builtin_bit_cast(float, v.z << 16);
    t[1] = __builtin_bit_cast(float, v.z & 0xFFFF0000u);
    a[2] += t;
    t[0] = __builtin_bit_cast(float, v.w << 16);
    t[1] = __builtin_bit_cast(float, v.w & 0xFFFF0000u);
    a[3] += t;
}

// ---- K0: zero the degree array ----
__global__ void zero_kernel(int* __restrict__ degi) {
    int i = blockIdx.x * 256 + threadIdx.x;
    if (i < N_NODES) degi[i] = 0;
}

// ---- K1: degree histogram; atomic RETURN kept as each edge's rank.
//      Also computes graph ranges from sorted batch. ----
__global__ void k1_kernel(const int* __restrict__ dst, const int* __restrict__ batch,
                          int* __restrict__ degi, int* __restrict__ rank,
                          int* __restrict__ gstart) {
    int b = blockIdx.x;
    if (b < EDGE_BLOCKS) {
        int e = b * 256 + threadIdx.x;   // exact, no guard
        rank[e] = atomicAdd(&degi[dst[e]], 1);
    } else {
        int i = (b - EDGE_BLOCKS) * 256 + threadIdx.x;
        if (i >= N_NODES) return;
        int bb = batch[i];
        int prev = (i == 0) ? -1 : batch[i - 1];
        for (int g = prev + 1; g <= bb; ++g) gstart[g] = i;
        if (i == N_NODES - 1)
            for (int g = bb + 1; g <= N_GRAPHS; ++g) gstart[g] = N_NODES;
    }
}

// ---- K2: single-kernel exclusive scan: each block self-computes its prefix ----
__global__ void scan_kernel(const int* __restrict__ degi, int* __restrict__ rowptr) {
    __shared__ int s[256];
    int t = threadIdx.x;
    int b = blockIdx.x;
    // prefix = sum of degi[0 .. b*256), strided-coalesced
    int pre = 0;
    for (int c = t; c < b * 256; c += 256) pre += degi[c];
    s[t] = pre;
    __syncthreads();
    for (int off = 128; off > 0; off >>= 1) {
        if (t < off) s[t] += s[t + off];
        __syncthreads();
    }
    int prefix = s[0];
    __syncthreads();
    int i = b * 256 + t;
    int v = (i < N_NODES) ? degi[i] : 0;
    s[t] = v;
    __syncthreads();
    for (int off = 1; off < 256; off <<= 1) {
        int add = (t >= off) ? s[t - off] : 0;
        __syncthreads();
        s[t] += add;
        __syncthreads();
    }
    if (i < N_NODES) rowptr[i] = prefix + s[t] - v;
    if (i == 0) rowptr[N_NODES] = N_EDGES;
}

// ---- K4: single-pass atomic-free CSR fill (pos = rowptr[dst]+rank) +
//      x->bf16 + weight prep, fused ----
__global__ void k4_kernel(const int* __restrict__ src, const int* __restrict__ dst,
                          const int* __restrict__ rank, const int* __restrict__ rowptr,
                          ushort_t* __restrict__ col,
                          const float* __restrict__ x, ushort_t* __restrict__ xh,
                          const float* __restrict__ w0, const float* __restrict__ w1,
                          const float* __restrict__ w2, const float* __restrict__ w3,
                          const float* __restrict__ w4, const float* __restrict__ w5,
                          const float* __restrict__ w6, short* __restrict__ wfrag) {
    int b = blockIdx.x;
    if (b < EDGE_BLOCKS) {
        int e = b * 256 + threadIdx.x;   // exact
        int d = dst[e];
        col[rowptr[d] + rank[e]] = (ushort_t)src[e];   // no atomics
    } else if (b < EDGE_BLOCKS + XSPLIT_BLOCKS) {
        int idx = (b - EDGE_BLOCKS) * 256 + threadIdx.x;   // float4 index, exact
        float4 v = ((const float4*)x)[idx];
        ushort4 o;
        o.x = bf16rne(v.x); o.y = bf16rne(v.y); o.z = bf16rne(v.z); o.w = bf16rne(v.w);
        ((ushort4*)xh)[idx] = o;
    } else {
        int tid = (b - EDGE_BLOCKS - XSPLIT_BLOCKS) * 256 + threadIdx.x;  // 0..7*4096-1
        int m = tid >> 12, t = tid & 4095;
        const float* W = (m == 0) ? w0 : (m == 1) ? w1 : (m == 2) ? w2 : (m == 3) ? w3
                       : (m == 4) ? w4 : (m == 5) ? w5 : w6;
        int j = t & 7, lane = (t >> 3) & 63, nt = (t >> 9) & 3, kt = t >> 11;
        int k = kt * 32 + ((lane >> 4) << 3) + j;
        int o = nt * 16 + (lane & 15);
        float v = W[k * 64 + o];
        unsigned short hi = bf16rne(v);
        unsigned short lo = bf16rne(v - bf2f(hi));
        wfrag[m * 8192 + t]        = (short)hi;
        wfrag[m * 8192 + 4096 + t] = (short)lo;
    }
}

// ---- pure gather over bf16 plane: one wave per node; 8 subgroups x 8 lanes ----
__global__ __launch_bounds__(512) void gather_kernel(
    const ushort_t* __restrict__ hplane, const int* __restrict__ rowptr,
    const ushort_t* __restrict__ col,
    ushort_t* __restrict__ mh, ushort_t* __restrict__ ml) {
    int gw   = (blockIdx.x * 512 + threadIdx.x) >> 6;   // node
    int lane = threadIdx.x & 63;
    int f = lane & 7;
    int g = lane >> 3;
    if (gw >= N_NODES) return;
    int beg = rowptr[gw], end = rowptr[gw + 1];
    const uint4* h16 = (const uint4*)hplane;

    f32x2 a[4] = {{0.f, 0.f}, {0.f, 0.f}, {0.f, 0.f}, {0.f, 0.f}};
    f32x2 b[4] = {{0.f, 0.f}, {0.f, 0.f}, {0.f, 0.f}, {0.f, 0.f}};
    int p = beg + g;
    for (; p + 8 < end; p += 16) {
        int s0 = col[p], s1 = col[p + 8];
        uint4 v0 = h16[s0 * 8 + f];
        uint4 v1 = h16[s1 * 8 + f];
        acc8p(a, v0);
        acc8p(b, v1);
    }
    if (p < end) {
        uint4 v = h16[col[p] * 8 + f];
        acc8p(a, v);
    }
#pragma unroll
    for (int j = 0; j < 4; ++j) a[j] += b[j];
    float r[8];
#pragma unroll
    for (int j = 0; j < 4; ++j) { r[2 * j] = a[j][0]; r[2 * j + 1] = a[j][1]; }
#pragma unroll
    for (int j = 0; j < 8; ++j) {
        float v = r[j];
        v += __shfl_xor(v, 8);
        v += __shfl_xor(v, 16);
        v += __shfl_xor(v, 32);
        r[j] = v;
    }
    if (g == 0) {
        float inv = 1.0f / fmaxf((float)(end - beg), 1.0f);
        unsigned hws[4], lws[4];
#pragma unroll
        for (int i = 0; i < 4; ++i) {
            float v0 = r[2 * i] * inv, v1 = r[2 * i + 1] * inv;
            unsigned short h0 = bf16rne(v0), h1 = bf16rne(v1);
            hws[i] = (unsigned)h0 | ((unsigned)h1 << 16);
            lws[i] = (unsigned)bf16rne(v0 - bf2f(h0)) |
                     ((unsigned)bf16rne(v1 - bf2f(h1)) << 16);
        }
        uint4 hv = {hws[0], hws[1], hws[2], hws[3]};
        uint4 lv = {lws[0], lws[1], lws[2], lws[3]};
        ((uint4*)mh)[gw * 8 + f] = hv;
        ((uint4*)ml)[gw * 8 + f] = lv;
    }
}

// ---- per-tile matmul: one wave per 16 nodes; no atomics. ----
template <int XMODE>
__global__ __launch_bounds__(64) void mm_kernel(
    const float* __restrict__ xf, const ushort_t* __restrict__ xhp,
    const ushort_t* __restrict__ mh, const ushort_t* __restrict__ ml,
    const short* __restrict__ wl, const short* __restrict__ wr, const short* __restrict__ wm,
    const float* __restrict__ blv, const float* __restrict__ bmv,
    ushort_t* __restrict__ hhout) {
    __shared__ short smh[16 * TPAD];
    __shared__ short sml[16 * TPAD];
    __shared__ short sxh[16 * TPAD];
    __shared__ short sxl[16 * TPAD];
    __shared__ short sth[16 * TPAD];
    __shared__ short stl[16 * TPAD];

    int lane = threadIdx.x;
    int f = lane & 15;
    int g = lane >> 4;
    int base = blockIdx.x * 16;

    {
        const uint4* mh16 = (const uint4*)mh;
        const uint4* ml16 = (const uint4*)ml;
#pragma unroll
        for (int i = 0; i < 2; ++i) {
            int c = i * 64 + lane;
            int r = c >> 3, cc = c & 7;
            *(uint4*)&smh[r * TPAD + cc * 8] = mh16[(base + r) * 8 + cc];
            *(uint4*)&sml[r * TPAD + cc * 8] = ml16[(base + r) * 8 + cc];
        }
    }
    if (XMODE == 1) {
        const uint4* xh16 = (const uint4*)xhp;
#pragma unroll
        for (int i = 0; i < 2; ++i) {
            int c = i * 64 + lane;
            int r = c >> 3, cc = c & 7;
            *(uint4*)&sxh[r * TPAD + cc * 8] = xh16[(base + r) * 8 + cc];
        }
    } else {
        const float4* x4 = (const float4*)xf;
#pragma unroll
        for (int i = 0; i < 4; ++i) {
            int idx = i * 64 + lane;
            int r = idx >> 4, c = idx & 15;
            float4 xv = x4[(size_t)(base + r) * 16 + c];
            unsigned short h0 = bf16rne(xv.x), h1 = bf16rne(xv.y),
                           h2 = bf16rne(xv.z), h3 = bf16rne(xv.w);
            uint2 hw, lw;
            hw.x = (unsigned)h0 | ((unsigned)h1 << 16);
            hw.y = (unsigned)h2 | ((unsigned)h3 << 16);
            lw.x = (unsigned)bf16rne(xv.x - bf2f(h0)) | ((unsigned)bf16rne(xv.y - bf2f(h1)) << 16);
            lw.y = (unsigned)bf16rne(xv.z - bf2f(h2)) | ((unsigned)bf16rne(xv.w - bf2f(h3)) << 16);
            *(uint2*)&sxh[r * TPAD + c * 4] = hw;
            *(uint2*)&sxl[r * TPAD + c * 4] = lw;
        }
    }

    short8 amh[2], aml[2], axh[2], axl[2];
#pragma unroll
    for (int kt = 0; kt < 2; ++kt) {
        int idx = f * TPAD + kt * 32 + g * 8;
        amh[kt] = *(const short8*)&smh[idx];
        aml[kt] = *(const short8*)&sml[idx];
        axh[kt] = *(const short8*)&sxh[idx];
        if (XMODE == 0) axl[kt] = *(const short8*)&sxl[idx];
    }
    const short* wlh = wl;
    const short* wll = wl + 4096;
    const short* wrh = wr;
    const short* wrl = wr + 4096;

#pragma unroll
    for (int nt = 0; nt < 4; ++nt) {
        f32x4 acc = {0.f, 0.f, 0.f, 0.f};
#pragma unroll
        for (int kt = 0; kt < 2; ++kt) {
            int fi = ((kt * 4 + nt) * 64 + lane) * 8;
            short8 blh = *(const short8*)&wlh[fi];
            short8 bll = *(const short8*)&wll[fi];
            short8 brh = *(const short8*)&wrh[fi];
            short8 brl = *(const short8*)&wrl[fi];
            acc = MFMA16(amh[kt], blh, acc);
            acc = MFMA16(aml[kt], blh, acc);
            acc = MFMA16(amh[kt], bll, acc);
            acc = MFMA16(axh[kt], brh, acc);
            if (XMODE == 0) acc = MFMA16(axl[kt], brh, acc);
            acc = MFMA16(axh[kt], brl, acc);
        }
        float bias = blv[nt * 16 + f];
#pragma unroll
        for (int r = 0; r < 4; ++r) {
            float tv = acc[r] + bias;
            unsigned short hi = bf16rne(tv);
            unsigned short lo = bf16rne(tv - bf2f(hi));
            int row = g * 4 + r;
            sth[row * TPAD + nt * 16 + f] = (short)hi;
            stl[row * TPAD + nt * 16 + f] = (short)lo;
        }
    }

    short8 ath[2], atl[2];
#pragma unroll
    for (int kt = 0; kt < 2; ++kt) {
        int idx = f * TPAD + kt * 32 + g * 8;
        ath[kt] = *(const short8*)&sth[idx];
        atl[kt] = *(const short8*)&stl[idx];
    }
    const short* wmh = wm;
    const short* wml = wm + 4096;
#pragma unroll
    for (int nt = 0; nt < 4; ++nt) {
        f32x4 acc = {0.f, 0.f, 0.f, 0.f};
#pragma unroll
        for (int kt = 0; kt < 2; ++kt) {
            int fi = ((kt * 4 + nt) * 64 + lane) * 8;
            short8 bh  = *(const short8*)&wmh[fi];
            short8 bl2 = *(const short8*)&wml[fi];
            acc = MFMA16(ath[kt], bh, acc);
            acc = MFMA16(atl[kt], bh, acc);
            acc = MFMA16(ath[kt], bl2, acc);
        }
        float bias = bmv[nt * 16 + f];
#pragma unroll
        for (int r = 0; r < 4; ++r) {
            float hv = acc[r] + bias;
            hv = hv > 0.f ? hv : 0.f;
            int row  = g * 4 + r;
            int node = base + row;
            hhout[node * D + nt * 16 + f] = bf16rne(hv);
        }
    }
}

// ---- fused segmented mean-pool + MLP over bf16 h planes ----
__global__ __launch_bounds__(256) void poolmlp_kernel(
    const ushort_t* __restrict__ h0, const ushort_t* __restrict__ h1,
    const ushort_t* __restrict__ h2, const int* __restrict__ gstart,
    const float* __restrict__ W1, const float* __restrict__ b1,
    const float* __restrict__ W2, const float* __restrict__ b2,
    float* __restrict__ out) {
    __shared__ float spart[4][3][64];
    __shared__ float sg[3 * 64];
    __shared__ float tt[64];
    int gr = blockIdx.x;
    int w = threadIdx.x >> 6, lane = threadIdx.x & 63;
    int beg = gstart[gr], end = gstart[gr + 1];
    float s0 = 0.f, s1 = 0.f, s2 = 0.f;
    for (int n = beg + w; n < end; n += 4) {
        s0 += bf2f(h0[n * 64 + lane]);
        s1 += bf2f(h1[n * 64 + lane]);
        s2 += bf2f(h2[n * 64 + lane]);
    }
    spart[w][0][lane] = s0; spart[w][1][lane] = s1; spart[w][2][lane] = s2;
    __syncthreads();
    if (w == 0) {
        float inv = 1.0f / fmaxf((float)(end - beg), 1.0f);
#pragma unroll
        for (int l = 0; l < 3; ++l)
            sg[l * 64 + lane] = (spart[0][l][lane] + spart[1][l][lane] +
                                 spart[2][l][lane] + spart[3][l][lane]) * inv;
    }
    __syncthreads();
    if (w == 0) {
        float acc = b1[lane];
#pragma unroll 8
        for (int k = 0; k < 3 * 64; ++k) acc += sg[k] * W1[k * 64 + lane];
        tt[lane] = fmaxf(acc, 0.f);
    }
    __syncthreads();
    if (w == 0 && lane < D_TARGET) {
        float acc = b2[lane];
#pragma unroll
        for (int k = 0; k < 64; ++k) acc += tt[k] * W2[k * D_TARGET + lane];
        out[gr * D_TARGET + lane] = acc;
    }
}

extern "C" void kernel_launch(void* const* d_in, const int* in_sizes, int n_in,
                              void* d_out, int out_size, void* d_ws, size_t ws_size,
                              hipStream_t stream) {
    const float* x     = (const float*)d_in[0];
    const int*   ei    = (const int*)d_in[1];
    const int*   src   = ei;
    const int*   dst   = ei + N_EDGES;
    const int*   batch = (const int*)d_in[2];

    const float* Wl[3] = {(const float*)d_in[3], (const float*)d_in[6], (const float*)d_in[9]};
    const float* bl[3] = {(const float*)d_in[4], (const float*)d_in[7], (const float*)d_in[10]};
    const float* Wr[3] = {(const float*)d_in[5], (const float*)d_in[8], (const float*)d_in[11]};
    const float* Wm = (const float*)d_in[12];
    const float* bm = (const float*)d_in[13];
    const float* W1 = (const float*)d_in[14];
    const float* b1 = (const float*)d_in[15];
    const float* W2 = (const float*)d_in[16];
    const float* b2 = (const float*)d_in[17];

    // workspace layout (4-byte words; sections 16B-aligned)
    int*      degi    = (int*)d_ws;                       // 50000
    int*      partial = degi + 50000;                     // 256 (unused, kept for layout)
    int*      rowptr  = partial + 256;                    // 50001 -> pad 50008
    int*      rank    = rowptr + 50008;                   // 800000
    int*      gstart  = rank + 800000;                    // 513 -> pad 520
    short*    wfrag   = (short*)(gstart + 520);           // 7*8192 shorts
    ushort_t* col     = (ushort_t*)(wfrag + 7 * 8192);    // 800000 ushort
    ushort_t* xh      = col + 800000;                     // 3.2M ushort
    ushort_t* mh      = xh + (size_t)N_NODES * D;
    ushort_t* ml      = mh + (size_t)N_NODES * D;
    ushort_t* hh0     = ml + (size_t)N_NODES * D;
    ushort_t* hh1     = hh0 + (size_t)N_NODES * D;
    ushort_t* hh2     = hh1 + (size_t)N_NODES * D;

    zero_kernel<<<NB_SCAN, 256, 0, stream>>>(degi);

    k1_kernel<<<EDGE_BLOCKS + NB_SCAN, 256, 0, stream>>>(dst, batch, degi, rank, gstart);
    scan_kernel<<<NB_SCAN, 256, 0, stream>>>(degi, rowptr);
    k4_kernel<<<EDGE_BLOCKS + XSPLIT_BLOCKS + WPREP_BLOCKS, 256, 0, stream>>>(
        src, dst, rank, rowptr, col, x, xh,
        Wl[0], Wr[0], Wl[1], Wr[1], Wl[2], Wr[2], Wm, wfrag);

    ushort_t* hplanes[4] = {xh, hh0, hh1, hh2};
    for (int l = 0; l < 3; ++l) {
        gather_kernel<<<(N_NODES * 64 + 511) / 512, 512, 0, stream>>>(
            hplanes[l], rowptr, col, mh, ml);
        if (l == 0)
            mm_kernel<0><<<N_NODES / 16, 64, 0, stream>>>(
                x, nullptr, mh, ml,
                wfrag + 0 * 8192, wfrag + 1 * 8192, wfrag + 6 * 8192,
                bl[0], bm, hh0);
        else
            mm_kernel<1><<<N_NODES / 16, 64, 0, stream>>>(
                nullptr, hplanes[l], mh, ml,
                wfrag + (2 * l) * 8192, wfrag + (2 * l + 1) * 8192, wfrag + 6 * 8192,
                bl[l], bm, hplanes[l + 1]);
    }

    poolmlp_kernel<<<N_GRAPHS, 256, 0, stream>>>(hh0, hh1, hh2, gstart, W1, b1, W2, b2,
                                                 (float*)d_out);
}

// Round 16
// 185.896 us; speedup vs baseline: 1.1245x; 1.1245x over previous
//
#include <hip/hip_runtime.h>

// GraphSAGE forward: bf16-plane storage, uint16 CSR col, rank-based atomic-free fill,
// xsplit+wprep folded into k1's latency bubbles, two-kernel scan (round-14 verified),
// atomic-free pooling, bf16x3-split MFMA matmuls.
#define N_NODES 50000
#define N_EDGES 800000
#define D 64
#define N_GRAPHS 512
#define D_TARGET 10
#define NB_SCAN ((N_NODES + 255) / 256)   // 196
#define TPAD 72                            // LDS tile row stride in bf16
#define EDGE_BLOCKS (N_EDGES / 256)        // 3125 (exact)
#define XSPLIT_BLOCKS EDGE_BLOCKS          // 3125 (one float4/thread, exact)
#define WPREP_BLOCKS 112                   // 7*4096/256

typedef __attribute__((ext_vector_type(8))) short short8;
typedef __attribute__((ext_vector_type(4))) float f32x4;
typedef unsigned short ushort_t;
#define MFMA16(a, b, c) __builtin_amdgcn_mfma_f32_16x16x32_bf16(a, b, c, 0, 0, 0)

__device__ inline unsigned short bf16rne(float f) {
    unsigned u = __builtin_bit_cast(unsigned, f);
    u += 0x7FFFu + ((u >> 16) & 1u);
    return (unsigned short)(u >> 16);
}
__device__ inline float bf2f(unsigned short h) {
    unsigned u = ((unsigned)h) << 16;
    return __builtin_bit_cast(float, u);
}
__device__ inline void acc8(float* a, uint4 v) {
    a[0] += __builtin_bit_cast(float, v.x << 16);
    a[1] += __builtin_bit_cast(float, v.x & 0xFFFF0000u);
    a[2] += __builtin_bit_cast(float, v.y << 16);
    a[3] += __builtin_bit_cast(float, v.y & 0xFFFF0000u);
    a[4] += __builtin_bit_cast(float, v.z << 16);
    a[5] += __builtin_bit_cast(float, v.z & 0xFFFF0000u);
    a[6] += __builtin_bit_cast(float, v.w << 16);
    a[7] += __builtin_bit_cast(float, v.w & 0xFFFF0000u);
}

// ---- K0: zero the degree array ----
__global__ void zero_kernel(int* __restrict__ degi) {
    int i = blockIdx.x * 256 + threadIdx.x;
    if (i < N_NODES) degi[i] = 0;
}

// ---- K1: rank-histogram (latency-bound atomics) + gstart + xsplit + wprep.
// The streaming xsplit/wprep blocks fill the CU bubbles left by atomic latency. ----
__global__ void k1_kernel(const int* __restrict__ dst, const int* __restrict__ batch,
                          int* __restrict__ degi, int* __restrict__ rank,
                          int* __restrict__ gstart,
                          const float* __restrict__ x, ushort_t* __restrict__ xh,
                          const float* __restrict__ w0, const float* __restrict__ w1,
                          const float* __restrict__ w2, const float* __restrict__ w3,
                          const float* __restrict__ w4, const float* __restrict__ w5,
                          const float* __restrict__ w6, short* __restrict__ wfrag) {
    int b = blockIdx.x;
    if (b < EDGE_BLOCKS) {
        int e = b * 256 + threadIdx.x;   // exact, no guard
        rank[e] = atomicAdd(&degi[dst[e]], 1);
    } else if (b < EDGE_BLOCKS + NB_SCAN) {
        int i = (b - EDGE_BLOCKS) * 256 + threadIdx.x;
        if (i >= N_NODES) return;
        int bb = batch[i];
        int prev = (i == 0) ? -1 : batch[i - 1];
        for (int g = prev + 1; g <= bb; ++g) gstart[g] = i;
        if (i == N_NODES - 1)
            for (int g = bb + 1; g <= N_GRAPHS; ++g) gstart[g] = N_NODES;
    } else if (b < EDGE_BLOCKS + NB_SCAN + XSPLIT_BLOCKS) {
        int idx = (b - EDGE_BLOCKS - NB_SCAN) * 256 + threadIdx.x;   // float4 index, exact
        float4 v = ((const float4*)x)[idx];
        ushort4 o;
        o.x = bf16rne(v.x); o.y = bf16rne(v.y); o.z = bf16rne(v.z); o.w = bf16rne(v.w);
        ((ushort4*)xh)[idx] = o;
    } else {
        int tid = (b - EDGE_BLOCKS - NB_SCAN - XSPLIT_BLOCKS) * 256 + threadIdx.x;
        int m = tid >> 12, t = tid & 4095;
        const float* W = (m == 0) ? w0 : (m == 1) ? w1 : (m == 2) ? w2 : (m == 3) ? w3
                       : (m == 4) ? w4 : (m == 5) ? w5 : w6;
        int j = t & 7, lane = (t >> 3) & 63, nt = (t >> 9) & 3, kt = t >> 11;
        int k = kt * 32 + ((lane >> 4) << 3) + j;
        int o = nt * 16 + (lane & 15);
        float v = W[k * 64 + o];
        unsigned short hi = bf16rne(v);
        unsigned short lo = bf16rne(v - bf2f(hi));
        wfrag[m * 8192 + t]        = (short)hi;
        wfrag[m * 8192 + 4096 + t] = (short)lo;
    }
}

// ---- K2: per-256-chunk sums ----
__global__ void scan_partials(const int* __restrict__ degi, int* __restrict__ partial) {
    __shared__ int s[256];
    int t = threadIdx.x;
    int i = blockIdx.x * 256 + t;
    s[t] = (i < N_NODES) ? degi[i] : 0;
    __syncthreads();
    for (int off = 128; off > 0; off >>= 1) {
        if (t < off) s[t] += s[t + off];
        __syncthreads();
    }
    if (t == 0) partial[blockIdx.x] = s[0];
}

// ---- K3: per-chunk inclusive scan with inline partial-prefix reduction ----
__global__ void scan_final(const int* __restrict__ degi, const int* __restrict__ partial,
                           int* __restrict__ rowptr) {
    __shared__ int s[256];
    __shared__ int sp[256];
    int t = threadIdx.x;
    int i = blockIdx.x * 256 + t;
    sp[t] = (t < blockIdx.x) ? partial[t] : 0;   // blockIdx.x <= 195 < 256
    __syncthreads();
    for (int off = 128; off > 0; off >>= 1) {
        if (t < off) sp[t] += sp[t + off];
        __syncthreads();
    }
    int prefix = sp[0];
    int v = (i < N_NODES) ? degi[i] : 0;
    s[t] = v;
    __syncthreads();
    for (int off = 1; off < 256; off <<= 1) {
        int add = (t >= off) ? s[t - off] : 0;
        __syncthreads();
        s[t] += add;
        __syncthreads();
    }
    if (i < N_NODES) rowptr[i] = prefix + s[t] - v;
    if (i == 0) rowptr[N_NODES] = N_EDGES;
}

// ---- K4: single-pass atomic-free CSR fill (pos = rowptr[dst]+rank) ----
__global__ void k4_kernel(const int* __restrict__ src, const int* __restrict__ dst,
                          const int* __restrict__ rank, const int* __restrict__ rowptr,
                          ushort_t* __restrict__ col) {
    int e = blockIdx.x * 256 + threadIdx.x;   // exact
    int d = dst[e];
    col[rowptr[d] + rank[e]] = (ushort_t)src[e];   // no atomics
}

// ---- pure gather over bf16 plane: one wave per node; 8 subgroups x 8 lanes ----
__global__ __launch_bounds__(512) void gather_kernel(
    const ushort_t* __restrict__ hplane, const int* __restrict__ rowptr,
    const ushort_t* __restrict__ col,
    ushort_t* __restrict__ mh, ushort_t* __restrict__ ml) {
    int gw   = (blockIdx.x * 512 + threadIdx.x) >> 6;   // node
    int lane = threadIdx.x & 63;
    int f = lane & 7;
    int g = lane >> 3;
    if (gw >= N_NODES) return;
    int beg = rowptr[gw], end = rowptr[gw + 1];
    const uint4* h16 = (const uint4*)hplane;

    float a[8] = {0.f, 0.f, 0.f, 0.f, 0.f, 0.f, 0.f, 0.f};
    float b[8] = {0.f, 0.f, 0.f, 0.f, 0.f, 0.f, 0.f, 0.f};
    int p = beg + g;
    for (; p + 8 < end; p += 16) {
        int s0 = col[p], s1 = col[p + 8];
        uint4 v0 = h16[s0 * 8 + f];
        uint4 v1 = h16[s1 * 8 + f];
        acc8(a, v0);
        acc8(b, v1);
    }
    if (p < end) {
        uint4 v = h16[col[p] * 8 + f];
        acc8(a, v);
    }
#pragma unroll
    for (int j = 0; j < 8; ++j) {
        float v = a[j] + b[j];
        v += __shfl_xor(v, 8);
        v += __shfl_xor(v, 16);
        v += __shfl_xor(v, 32);
        a[j] = v;
    }
    if (g == 0) {
        float inv = 1.0f / fmaxf((float)(end - beg), 1.0f);
        unsigned hws[4], lws[4];
#pragma unroll
        for (int i = 0; i < 4; ++i) {
            float v0 = a[2 * i] * inv, v1 = a[2 * i + 1] * inv;
            unsigned short h0 = bf16rne(v0), h1 = bf16rne(v1);
            hws[i] = (unsigned)h0 | ((unsigned)h1 << 16);
            lws[i] = (unsigned)bf16rne(v0 - bf2f(h0)) |
                     ((unsigned)bf16rne(v1 - bf2f(h1)) << 16);
        }
        uint4 hv = {hws[0], hws[1], hws[2], hws[3]};
        uint4 lv = {lws[0], lws[1], lws[2], lws[3]};
        ((uint4*)mh)[gw * 8 + f] = hv;
        ((uint4*)ml)[gw * 8 + f] = lv;
    }
}

// ---- per-tile matmul: one wave per 16 nodes; no atomics. ----
template <int XMODE>
__global__ __launch_bounds__(64) void mm_kernel(
    const float* __restrict__ xf, const ushort_t* __restrict__ xhp,
    const ushort_t* __restrict__ mh, const ushort_t* __restrict__ ml,
    const short* __restrict__ wl, const short* __restrict__ wr, const short* __restrict__ wm,
    const float* __restrict__ blv, const float* __restrict__ bmv,
    ushort_t* __restrict__ hhout) {
    __shared__ short smh[16 * TPAD];
    __shared__ short sml[16 * TPAD];
    __shared__ short sxh[16 * TPAD];
    __shared__ short sxl[16 * TPAD];
    __shared__ short sth[16 * TPAD];
    __shared__ short stl[16 * TPAD];

    int lane = threadIdx.x;
    int f = lane & 15;
    int g = lane >> 4;
    int base = blockIdx.x * 16;

    {
        const uint4* mh16 = (const uint4*)mh;
        const uint4* ml16 = (const uint4*)ml;
#pragma unroll
        for (int i = 0; i < 2; ++i) {
            int c = i * 64 + lane;
            int r = c >> 3, cc = c & 7;
            *(uint4*)&smh[r * TPAD + cc * 8] = mh16[(base + r) * 8 + cc];
            *(uint4*)&sml[r * TPAD + cc * 8] = ml16[(base + r) * 8 + cc];
        }
    }
    if (XMODE == 1) {
        const uint4* xh16 = (const uint4*)xhp;
#pragma unroll
        for (int i = 0; i < 2; ++i) {
            int c = i * 64 + lane;
            int r = c >> 3, cc = c & 7;
            *(uint4*)&sxh[r * TPAD + cc * 8] = xh16[(base + r) * 8 + cc];
        }
    } else {
        const float4* x4 = (const float4*)xf;
#pragma unroll
        for (int i = 0; i < 4; ++i) {
            int idx = i * 64 + lane;
            int r = idx >> 4, c = idx & 15;
            float4 xv = x4[(size_t)(base + r) * 16 + c];
            unsigned short h0 = bf16rne(xv.x), h1 = bf16rne(xv.y),
                           h2 = bf16rne(xv.z), h3 = bf16rne(xv.w);
            uint2 hw, lw;
            hw.x = (unsigned)h0 | ((unsigned)h1 << 16);
            hw.y = (unsigned)h2 | ((unsigned)h3 << 16);
            lw.x = (unsigned)bf16rne(xv.x - bf2f(h0)) | ((unsigned)bf16rne(xv.y - bf2f(h1)) << 16);
            lw.y = (unsigned)bf16rne(xv.z - bf2f(h2)) | ((unsigned)bf16rne(xv.w - bf2f(h3)) << 16);
            *(uint2*)&sxh[r * TPAD + c * 4] = hw;
            *(uint2*)&sxl[r * TPAD + c * 4] = lw;
        }
    }

    short8 amh[2], aml[2], axh[2], axl[2];
#pragma unroll
    for (int kt = 0; kt < 2; ++kt) {
        int idx = f * TPAD + kt * 32 + g * 8;
        amh[kt] = *(const short8*)&smh[idx];
        aml[kt] = *(const short8*)&sml[idx];
        axh[kt] = *(const short8*)&sxh[idx];
        if (XMODE == 0) axl[kt] = *(const short8*)&sxl[idx];
    }
    const short* wlh = wl;
    const short* wll = wl + 4096;
    const short* wrh = wr;
    const short* wrl = wr + 4096;

#pragma unroll
    for (int nt = 0; nt < 4; ++nt) {
        f32x4 acc = {0.f, 0.f, 0.f, 0.f};
#pragma unroll
        for (int kt = 0; kt < 2; ++kt) {
            int fi = ((kt * 4 + nt) * 64 + lane) * 8;
            short8 blh = *(const short8*)&wlh[fi];
            short8 bll = *(const short8*)&wll[fi];
            short8 brh = *(const short8*)&wrh[fi];
            short8 brl = *(const short8*)&wrl[fi];
            acc = MFMA16(amh[kt], blh, acc);
            acc = MFMA16(aml[kt], blh, acc);
            acc = MFMA16(amh[kt], bll, acc);
            acc = MFMA16(axh[kt], brh, acc);
            if (XMODE == 0) acc = MFMA16(axl[kt], brh, acc);
            acc = MFMA16(axh[kt], brl, acc);
        }
        float bias = blv[nt * 16 + f];
#pragma unroll
        for (int r = 0; r < 4; ++r) {
            float tv = acc[r] + bias;
            unsigned short hi = bf16rne(tv);
            unsigned short lo = bf16rne(tv - bf2f(hi));
            int row = g * 4 + r;
            sth[row * TPAD + nt * 16 + f] = (short)hi;
            stl[row * TPAD + nt * 16 + f] = (short)lo;
        }
    }

    short8 ath[2], atl[2];
#pragma unroll
    for (int kt = 0; kt < 2; ++kt) {
        int idx = f * TPAD + kt * 32 + g * 8;
        ath[kt] = *(const short8*)&sth[idx];
        atl[kt] = *(const short8*)&stl[idx];
    }
    const short* wmh = wm;
    const short* wml = wm + 4096;
#pragma unroll
    for (int nt = 0; nt < 4; ++nt) {
        f32x4 acc = {0.f, 0.f, 0.f, 0.f};
#pragma unroll
        for (int kt = 0; kt < 2; ++kt) {
            int fi = ((kt * 4 + nt) * 64 + lane) * 8;
            short8 bh  = *(const short8*)&wmh[fi];
            short8 bl2 = *(const short8*)&wml[fi];
            acc = MFMA16(ath[kt], bh, acc);
            acc = MFMA16(atl[kt], bh, acc);
            acc = MFMA16(ath[kt], bl2, acc);
        }
        float bias = bmv[nt * 16 + f];
#pragma unroll
        for (int r = 0; r < 4; ++r) {
            float hv = acc[r] + bias;
            hv = hv > 0.f ? hv : 0.f;
            int row  = g * 4 + r;
            int node = base + row;
            hhout[node * D + nt * 16 + f] = bf16rne(hv);
        }
    }
}

// ---- fused segmented mean-pool + MLP over bf16 h planes ----
__global__ __launch_bounds__(256) void poolmlp_kernel(
    const ushort_t* __restrict__ h0, const ushort_t* __restrict__ h1,
    const ushort_t* __restrict__ h2, const int* __restrict__ gstart,
    const float* __restrict__ W1, const float* __restrict__ b1,
    const float* __restrict__ W2, const float* __restrict__ b2,
    float* __restrict__ out) {
    __shared__ float spart[4][3][64];
    __shared__ float sg[3 * 64];
    __shared__ float tt[64];
    int gr = blockIdx.x;
    int w = threadIdx.x >> 6, lane = threadIdx.x & 63;
    int beg = gstart[gr], end = gstart[gr + 1];
    float s0 = 0.f, s1 = 0.f, s2 = 0.f;
    for (int n = beg + w; n < end; n += 4) {
        s0 += bf2f(h0[n * 64 + lane]);
        s1 += bf2f(h1[n * 64 + lane]);
        s2 += bf2f(h2[n * 64 + lane]);
    }
    spart[w][0][lane] = s0; spart[w][1][lane] = s1; spart[w][2][lane] = s2;
    __syncthreads();
    if (w == 0) {
        float inv = 1.0f / fmaxf((float)(end - beg), 1.0f);
#pragma unroll
        for (int l = 0; l < 3; ++l)
            sg[l * 64 + lane] = (spart[0][l][lane] + spart[1][l][lane] +
                                 spart[2][l][lane] + spart[3][l][lane]) * inv;
    }
    __syncthreads();
    if (w == 0) {
        float acc = b1[lane];
#pragma unroll 8
        for (int k = 0; k < 3 * 64; ++k) acc += sg[k] * W1[k * 64 + lane];
        tt[lane] = fmaxf(acc, 0.f);
    }
    __syncthreads();
    if (w == 0 && lane < D_TARGET) {
        float acc = b2[lane];
#pragma unroll
        for (int k = 0; k < 64; ++k) acc += tt[k] * W2[k * D_TARGET + lane];
        out[gr * D_TARGET + lane] = acc;
    }
}

extern "C" void kernel_launch(void* const* d_in, const int* in_sizes, int n_in,
                              void* d_out, int out_size, void* d_ws, size_t ws_size,
                              hipStream_t stream) {
    const float* x     = (const float*)d_in[0];
    const int*   ei    = (const int*)d_in[1];
    const int*   src   = ei;
    const int*   dst   = ei + N_EDGES;
    const int*   batch = (const int*)d_in[2];

    const float* Wl[3] = {(const float*)d_in[3], (const float*)d_in[6], (const float*)d_in[9]};
    const float* bl[3] = {(const float*)d_in[4], (const float*)d_in[7], (const float*)d_in[10]};
    const float* Wr[3] = {(const float*)d_in[5], (const float*)d_in[8], (const float*)d_in[11]};
    const float* Wm = (const float*)d_in[12];
    const float* bm = (const float*)d_in[13];
    const float* W1 = (const float*)d_in[14];
    const float* b1 = (const float*)d_in[15];
    const float* W2 = (const float*)d_in[16];
    const float* b2 = (const float*)d_in[17];

    // workspace layout (4-byte words; sections 16B-aligned)
    int*      degi    = (int*)d_ws;                       // 50000
    int*      partial = degi + 50000;                     // 256
    int*      rowptr  = partial + 256;                    // 50001 -> pad 50008
    int*      rank    = rowptr + 50008;                   // 800000
    int*      gstart  = rank + 800000;                    // 513 -> pad 520
    short*    wfrag   = (short*)(gstart + 520);           // 7*8192 shorts
    ushort_t* col     = (ushort_t*)(wfrag + 7 * 8192);    // 800000 ushort
    ushort_t* xh      = col + 800000;                     // 3.2M ushort
    ushort_t* mh      = xh + (size_t)N_NODES * D;
    ushort_t* ml      = mh + (size_t)N_NODES * D;
    ushort_t* hh0     = ml + (size_t)N_NODES * D;
    ushort_t* hh1     = hh0 + (size_t)N_NODES * D;
    ushort_t* hh2     = hh1 + (size_t)N_NODES * D;

    zero_kernel<<<NB_SCAN, 256, 0, stream>>>(degi);

    k1_kernel<<<EDGE_BLOCKS + NB_SCAN + XSPLIT_BLOCKS + WPREP_BLOCKS, 256, 0, stream>>>(
        dst, batch, degi, rank, gstart, x, xh,
        Wl[0], Wr[0], Wl[1], Wr[1], Wl[2], Wr[2], Wm, wfrag);
    scan_partials<<<NB_SCAN, 256, 0, stream>>>(degi, partial);
    scan_final<<<NB_SCAN, 256, 0, stream>>>(degi, partial, rowptr);
    k4_kernel<<<EDGE_BLOCKS, 256, 0, stream>>>(src, dst, rank, rowptr, col);

    ushort_t* hplanes[4] = {xh, hh0, hh1, hh2};
    for (int l = 0; l < 3; ++l) {
        gather_kernel<<<(N_NODES * 64 + 511) / 512, 512, 0, stream>>>(
            hplanes[l], rowptr, col, mh, ml);
        if (l == 0)
            mm_kernel<0><<<N_NODES / 16, 64, 0, stream>>>(
                x, nullptr, mh, ml,
                wfrag + 0 * 8192, wfrag + 1 * 8192, wfrag + 6 * 8192,
                bl[0], bm, hh0);
        else
            mm_kernel<1><<<N_NODES / 16, 64, 0, stream>>>(
                nullptr, hplanes[l], mh, ml,
                wfrag + (2 * l) * 8192, wfrag + (2 * l + 1) * 8192, wfrag + 6 * 8192,
                bl[l], bm, hplanes[l + 1]);
    }

    poolmlp_kernel<<<N_GRAPHS, 256, 0, stream>>>(hh0, hh1, hh2, gstart, W1, b1, W2, b2,
                                                 (float*)d_out);
}